// Round 2
// baseline (8783.743 us; speedup 1.0000x reference)
//
#include <hip/hip_runtime.h>
#include <hip/hip_bf16.h>

// ---------------------------------------------------------------------------
// MA_LSTM on MI355X (gfx950) — persistent kernel, v2.
//   blocks 0..159 ("A"): z-GEMM partials. 40 col-groups x 4 K-quarters.
//       N-tile 128, K=512 (h or c half, hi+lo bf16), weights+kt in LDS (147KB).
//       Each wave owns a 32-col slab (no cross-wave reduction).
//   blocks 160..223 ("B"): gates (1 batch row each, sums 4 z-partials + bias)
//       + agg-GEMM (aggT 16 cols in LDS, 96KB) + state update.
// Barriers: per-block flag arrays (monotone t+1), release-fence + relaxed
// atomic store to OWN flag; waiters poll per-lane relaxed atomic loads.
// NO atomic RMW -> no same-line serialization (v1's 60us/step spin).
// Grid 224 <= 256 CUs at 1 block/CU (LDS-limited) -> co-resident, plain launch.
// ---------------------------------------------------------------------------

typedef short  bf16x8 __attribute__((ext_vector_type(8)));
typedef float  f32x4  __attribute__((ext_vector_type(4)));
typedef __hip_bfloat16 bf16;

#define U 1024
#define BATCH 64
#define TSTEPS 128
#define DIM 256
#define N5 5120
#define K2 2048   // h(1024) + c(1024)

// ---- workspace layout (bytes) ----
#define OFF_WRC   0u                       // bf16 [5120][2048]  (Wr^T | Wc^T)
#define OFF_KT    20971520u                // bf16 [5120][256]   kernel^T
#define OFF_AGGT  23592960u                // bf16 [1024][3072]  aggregation^T
#define OFF_XBF   29884416u                // bf16 [64][128][256] x in bf16
#define OFF_ZP    34078720u                // f32  [4][64][5120] z partials
#define OFF_ABUF  39321600u                // bf16 [4][64][1024] h_hi,h_lo,c_hi,c_lo
#define OFF_C32   39845888u                // f32  [64][1024]
#define OFF_OBUF  40108032u                // bf16 [64][3072]
#define OFF_SCAL  40501248u                // f32  [8]
#define OFF_CTR   40501504u                // int flags (4KB zone)

#define NBLK_A 160
#define NBLK_B 64
#define NBLK   224

#define RS_B 6144   // LDS row stride bytes, B-role aggT: 3072 bf16
#define KT_OFF 131072  // LDS byte offset of kt slab in A-role

#define MFMA16(a,b,c) __builtin_amdgcn_mfma_f32_16x16x32_bf16((a),(b),(c),0,0,0)

// ---------------------------------------------------------------------------
__global__ __launch_bounds__(256) void k_xconv(const float* __restrict__ in,
                                               bf16* __restrict__ o, int n4) {
    const int i = blockIdx.x * 256 + threadIdx.x;
    if (i < n4) {
        const float4 v = ((const float4*)in)[i];
        bf16 tmp[4] = {__float2bfloat16(v.x), __float2bfloat16(v.y),
                       __float2bfloat16(v.z), __float2bfloat16(v.w)};
        ((uint2*)o)[i] = *(const uint2*)tmp;
    }
}

// ---------------------------------------------------------------------------
// tiled transpose + fp32->bf16: out[c*out_stride + out_off + r] = bf16(in[r*C+c])
__global__ __launch_bounds__(256) void k_transpose(const float* __restrict__ in,
                                                   bf16* __restrict__ out,
                                                   int C, int out_stride, int out_off) {
    __shared__ bf16 tile[64][65];
    const int tc = blockIdx.x * 64, tr = blockIdx.y * 64;
    const int tx = threadIdx.x & 63, ty0 = threadIdx.x >> 6;
#pragma unroll
    for (int i = 0; i < 64; i += 4)
        tile[ty0 + i][tx] = __float2bfloat16(in[(tr + ty0 + i) * C + tc + tx]);
    __syncthreads();
#pragma unroll
    for (int i = 0; i < 64; i += 4)
        out[(tc + ty0 + i) * out_stride + out_off + tr + tx] = tile[tx][ty0 + i];
}

// ---------------------------------------------------------------------------
struct AttPtrs { const float* p[12]; };

__global__ __launch_bounds__(256) void k_scal(AttPtrs ap, float* __restrict__ scal) {
    __shared__ float red[256];
    const int tid = threadIdx.x;
    for (int q = 0; q < 6; ++q) {
        const float* l = ap.p[2 * q];
        const float* r = ap.p[2 * q + 1];
        float s = 0.f;
        for (int i = tid; i < 1024; i += 256)
            s += l[i] * r[i];
        red[tid] = s; __syncthreads();
        for (int o = 128; o > 0; o >>= 1) {
            if (tid < o) red[tid] += red[tid + o];
            __syncthreads();
        }
        if (tid == 0) scal[q] = red[0];
        __syncthreads();
    }
}

// ---------------------------------------------------------------------------
// block collectives (256 threads = 4 waves)
__device__ __forceinline__ float wave_sum(float v) {
#pragma unroll
    for (int o = 32; o > 0; o >>= 1) v += __shfl_xor(v, o, 64);
    return v;
}
__device__ __forceinline__ float wave_max(float v) {
#pragma unroll
    for (int o = 32; o > 0; o >>= 1) v = fmaxf(v, __shfl_xor(v, o, 64));
    return v;
}
__device__ __forceinline__ float wave_scan(float v, int lane) {
#pragma unroll
    for (int o = 1; o < 64; o <<= 1) {
        float n = __shfl_up(v, o, 64);
        if (lane >= o) v += n;
    }
    return v;
}
__device__ __forceinline__ float block_sum(float v, float* sm4, int w, int lane) {
    float s = wave_sum(v);
    if (lane == 0) sm4[w] = s;
    __syncthreads();
    float r = sm4[0] + sm4[1] + sm4[2] + sm4[3];
    __syncthreads();
    return r;
}
__device__ __forceinline__ float block_max(float v, float* sm4, int w, int lane) {
    float s = wave_max(v);
    if (lane == 0) sm4[w] = s;
    __syncthreads();
    float r = fmaxf(fmaxf(sm4[0], sm4[1]), fmaxf(sm4[2], sm4[3]));
    __syncthreads();
    return r;
}
__device__ __forceinline__ float block_scan(float v, float* sm4, int w, int lane, float* total) {
    float ws = wave_scan(v, lane);
    if (lane == 63) sm4[w] = ws;
    __syncthreads();
    float base = 0.f;
    if (w > 0) base += sm4[0];
    if (w > 1) base += sm4[1];
    if (w > 2) base += sm4[2];
    *total = sm4[0] + sm4[1] + sm4[2] + sm4[3];
    __syncthreads();
    return base + ws;
}
__device__ __forceinline__ float sigm(float x) { return 1.f / (1.f + __expf(-x)); }

// ---------------------------------------------------------------------------
// flag-based split barriers (no atomic RMW).
// signal: block's stores drained (syncthreads) -> release fence (wbl2) ->
//         relaxed agent store of t+1 to OWN flag (goes to L3 coherence point).
// wait:   wave 0 polls n flags with per-lane relaxed agent loads; when all
//         >= target, acquire fence (inv L1/L2) then syncthreads.
__device__ __forceinline__ void signal_flag(int* f, int v) {
    __syncthreads();
    if (threadIdx.x == 0) {
        __threadfence();   // release: publish this block's global writes
        __hip_atomic_store(f, v, __ATOMIC_RELAXED, __HIP_MEMORY_SCOPE_AGENT);
    }
}
__device__ __forceinline__ void wait_ge(int* f, int n, int tgt) {
    if (threadIdx.x < 64) {
        for (;;) {
            int mn = 0x7fffffff;
            for (int i = threadIdx.x; i < n; i += 64) {
                int v = __hip_atomic_load(f + i, __ATOMIC_RELAXED, __HIP_MEMORY_SCOPE_AGENT);
                if (v < mn) mn = v;
            }
            if (__all(mn >= tgt)) break;
            __builtin_amdgcn_s_sleep(2);
        }
        __threadfence();   // acquire: invalidate stale L1/L2 before data reads
    }
    __syncthreads();
}

// swizzled LDS read (XOR (row&7)<<4 spreads stride-pow2 rows over 8 16B slots)
__device__ __forceinline__ bf16x8 lds_rd(const char* s, int nloc, int kb, int rs) {
    return *(const bf16x8*)(s + nloc * rs + (kb ^ ((nloc & 7) << 4)));
}

// ---------------------------------------------------------------------------
__global__ __launch_bounds__(256, 1) void k_persist(
    const bf16* __restrict__ xbf, const bf16* __restrict__ kt,
    const bf16* __restrict__ wrct, const bf16* __restrict__ aggt,
    float* __restrict__ zp, bf16* __restrict__ abuf,
    float* __restrict__ c32, bf16* __restrict__ obuf,
    const float* __restrict__ scal, const float* __restrict__ bias,
    float* __restrict__ out, int* __restrict__ ctr)
{
    __shared__ __align__(16) char smem[147456];   // A: 128KB weights + 16KB kt
    __shared__ float sm4[4];

    const int bid = blockIdx.x, tid = threadIdx.x;
    const int w = tid >> 6, lane = tid & 63;
    const int ml = lane & 15, q = lane >> 4;
    int* fA = ctr;          // [160] z-partials ready (value t+1)
    int* fB = ctr + 256;    // [64]  O rows ready
    int* fC = ctr + 512;    // [64]  h,c state ready

    if (bid < NBLK_A) {
        // =================== role A: z-GEMM partial ====================
        const int cg = bid >> 2;            // col group: cols cg*128..+127
        const int kq = bid & 3;             // K quarter: 0,1=h halves; 2,3=c halves
        const int n0 = cg * 128;
        const int kwbase = (kq < 2) ? kq * 512 : 1024 + (kq - 2) * 512;
        const int kA0 = (kq & 1) * 512;     // offset within h (or c) plane

        // stage weights [128][512] bf16, swizzled, rs=1024B
        for (int i = 0; i < 32; ++i) {
            const int cid = i * 256 + tid;
            const int row = cid >> 6, k = (cid & 63) * 8;
            bf16x8 v = *(const bf16x8*)(wrct + (size_t)(n0 + row) * K2 + kwbase + k);
            *(bf16x8*)(smem + row * 1024 + ((k * 2) ^ ((row & 7) << 4))) = v;
        }
        // stage kt slab [128][64] bf16, swizzled, rs=128B
        for (int i = 0; i < 4; ++i) {
            const int cid = i * 256 + tid;
            const int row = cid >> 3, k = (cid & 7) * 8;
            bf16x8 v = *(const bf16x8*)(kt + (size_t)(n0 + row) * DIM + kq * 64 + k);
            *(bf16x8*)(smem + KT_OFF + row * 128 + ((k * 2) ^ ((row & 7) << 4))) = v;
        }
        __syncthreads();

        const bf16* hiP = abuf + (kq < 2 ? 0 : 2) * 65536;
        const bf16* loP = abuf + (kq < 2 ? 1 : 3) * 65536;
        const int rowLDS0 = w * 32 + ml;       // this wave's LDS B rows
        float* zpq = zp + (size_t)kq * 64 * N5;
        const int colA = n0 + w * 32 + ml;
        const int colB = colA + 16;

#define LOADC(C, B) do { _Pragma("unroll") \
        for (int mi_ = 0; mi_ < 4; ++mi_) { \
            const int off_ = (mi_ * 16 + ml) * U + kA0 + (C) * 32 + q * 8; \
            ah[B][mi_] = *(const bf16x8*)(hiP + off_); \
            al[B][mi_] = *(const bf16x8*)(loP + off_); \
        } } while (0)

        for (int t = 0; t < TSTEPS; ++t) {
            f32x4 acc[8];
#pragma unroll
            for (int i = 0; i < 8; ++i) acc[i] = (f32x4){0.f, 0.f, 0.f, 0.f};

            // ---- x @ kernel slice (64 K per quarter): independent of state
#pragma unroll
            for (int cx = 0; cx < 2; ++cx) {
                const int kx = kq * 64 + cx * 32 + q * 8;
                bf16x8 ax[4];
#pragma unroll
                for (int mi = 0; mi < 4; ++mi)
                    ax[mi] = *(const bf16x8*)(xbf + ((size_t)(mi * 16 + ml) * TSTEPS + t) * DIM + kx);
                const bf16x8 b0 = lds_rd(smem + KT_OFF, rowLDS0, cx * 64 + q * 16, 128);
                const bf16x8 b1 = lds_rd(smem + KT_OFF, rowLDS0 + 16, cx * 64 + q * 16, 128);
#pragma unroll
                for (int mi = 0; mi < 4; ++mi) {
                    acc[mi * 2 + 0] = MFMA16(ax[mi], b0, acc[mi * 2 + 0]);
                    acc[mi * 2 + 1] = MFMA16(ax[mi], b1, acc[mi * 2 + 1]);
                }
            }

            wait_ge(fC, NBLK_B, t);          // state of step t-1 ready

            // ---- (h|c) quarter, hi+lo: 16 k-chunks, 2-deep prefetch
            {
                bf16x8 ah[3][4], al[3][4];
                LOADC(0, 0);
                LOADC(1, 1);
#pragma unroll
                for (int ch = 0; ch < 16; ++ch) {
                    if (ch < 14) LOADC(ch + 2, (ch + 2) % 3);
                    const bf16x8 b0 = lds_rd(smem, rowLDS0, ch * 64 + q * 16, 1024);
                    const bf16x8 b1 = lds_rd(smem, rowLDS0 + 16, ch * 64 + q * 16, 1024);
                    const int B_ = ch % 3;
#pragma unroll
                    for (int mi = 0; mi < 4; ++mi) {
                        acc[mi * 2 + 0] = MFMA16(ah[B_][mi], b0, acc[mi * 2 + 0]);
                        acc[mi * 2 + 1] = MFMA16(ah[B_][mi], b1, acc[mi * 2 + 1]);
                        acc[mi * 2 + 0] = MFMA16(al[B_][mi], b0, acc[mi * 2 + 0]);
                        acc[mi * 2 + 1] = MFMA16(al[B_][mi], b1, acc[mi * 2 + 1]);
                    }
                }
            }

            // ---- epilogue: write partial z (bias added on B side)
#pragma unroll
            for (int mi = 0; mi < 4; ++mi)
#pragma unroll
                for (int r = 0; r < 4; ++r) {
                    const int row = mi * 16 + q * 4 + r;
                    zpq[row * N5 + colA] = acc[mi * 2 + 0][r];
                    zpq[row * N5 + colB] = acc[mi * 2 + 1][r];
                }
            signal_flag(fA + bid, t + 1);
        }
#undef LOADC
    } else {
        // ========= role B: gates (row rb) + agg-GEMM (16 u-cols) + state =========
        const int rb = bid - NBLK_A;
        const int n0b = rb * 16;
        // stage aggT tile [16][3072] bf16, swizzled, rs=6144B
        for (int i = 0; i < 24; ++i) {
            const int cid = i * 256 + tid;
            const int nloc = cid / 384, kc = cid - nloc * 384;
            const int k = kc * 8;
            bf16x8 v = *(const bf16x8*)(aggt + (size_t)(n0b + nloc) * 3072 + k);
            *(bf16x8*)(smem + nloc * RS_B + ((k * 2) ^ ((nloc & 7) << 4))) = v;
        }
        __syncthreads();

        const float s_ud = scal[0], s_ur = scal[1], s_ru = scal[2],
                    s_rd = scal[3], s_du = scal[4], s_dr = scal[5];
        const int rowA = w * 16 + ml;
        const bf16* orow = obuf + rowA * 3072;

#define LOADO(G, BUF) do { _Pragma("unroll") \
        for (int j_ = 0; j_ < 8; ++j_) \
            ob[BUF][j_] = *(const bf16x8*)(orow + ((G) * 8 + j_) * 32 + q * 8); \
        } while (0)

        for (int t = 0; t < TSTEPS; ++t) {
            wait_ge(fA, 96, t + 1);          // z cols 0..3071 ready (cg 0..23)
            // ---------------- P2: gates for batch row rb ----------------
            {
                f32x4 zu = {0.f,0.f,0.f,0.f}, zd = {0.f,0.f,0.f,0.f}, zn = {0.f,0.f,0.f,0.f};
#pragma unroll
                for (int kqi = 0; kqi < 4; ++kqi) {
                    const f32x4* bp = (const f32x4*)(zp + (size_t)kqi * 64 * N5 + rb * N5);
                    zu += bp[tid];
                    zd += bp[256 + tid];
                    zn += bp[512 + tid];
                }
                zu += ((const f32x4*)bias)[tid];
                zd += ((const f32x4*)bias)[256 + tid];
                zn += ((const f32x4*)bias)[512 + tid];

                float mup = block_max(fmaxf(fmaxf(zu[0], zu[1]), fmaxf(zu[2], zu[3])), sm4, w, lane);
                const float e0 = __expf(zu[0] - mup), e1 = __expf(zu[1] - mup),
                            e2 = __expf(zu[2] - mup), e3 = __expf(zu[3] - mup);
                float totu;
                float inclu = block_scan(e0 + e1 + e2 + e3, sm4, w, lane, &totu);
                const float exclu = inclu - (e0 + e1 + e2 + e3);
                const float inv_u = 1.f / totu;
                const float u0 = (exclu + e0) * inv_u;
                const float u1 = (exclu + e0 + e1) * inv_u;
                const float u2 = (exclu + e0 + e1 + e2) * inv_u;
                const float u3 = (exclu + e0 + e1 + e2 + e3) * inv_u;

                float mdn = block_max(fmaxf(fmaxf(zd[0], zd[1]), fmaxf(zd[2], zd[3])), sm4, w, lane);
                const float f0 = __expf(zd[0] - mdn), f1 = __expf(zd[1] - mdn),
                            f2 = __expf(zd[2] - mdn), f3 = __expf(zd[3] - mdn);
                float totd;
                float incld = block_scan(f0 + f1 + f2 + f3, sm4, w, lane, &totd);
                const float excld = incld - (f0 + f1 + f2 + f3);
                const float inv_d = 1.f / totd;
                const float d0 = (totd - excld) * inv_d;
                const float d1 = (totd - excld - f0) * inv_d;
                const float d2 = (totd - excld - f0 - f1) * inv_d;
                const float d3 = (totd - excld - f0 - f1 - f2) * inv_d;

                const float du = block_sum(d0 * u0 + d1 * u1 + d2 * u2 + d3 * u3, sm4, w, lane);
                const float ru = block_sum(zn[0] * u0 + zn[1] * u1 + zn[2] * u2 + zn[3] * u3, sm4, w, lane);
                const float dr = block_sum(d0 * zn[0] + d1 * zn[1] + d2 * zn[2] + d3 * zn[3], sm4, w, lane);

                bf16* orw = obuf + rb * 3072;
                const int j0 = tid * 4;
                const float uu[4] = {u0, u1, u2, u3};
                const float dd[4] = {d0, d1, d2, d3};
                const float rr[4] = {zn[0], zn[1], zn[2], zn[3]};
                bf16 t1[4], t2[4], t3[4];
#pragma unroll
                for (int i = 0; i < 4; ++i) {
                    t1[i] = __float2bfloat16(sigm(s_ud * uu[i] * du) + sigm(s_ur * uu[i] * ru));
                    t2[i] = __float2bfloat16(sigm(s_ru * rr[i] * ru) + sigm(s_rd * rr[i] * dr));
                    t3[i] = __float2bfloat16(sigm(s_du * dd[i] * du) + sigm(s_dr * dd[i] * dr));
                }
                *(uint2*)(orw + j0)         = *(uint2*)t1;
                *(uint2*)(orw + U + j0)     = *(uint2*)t2;
                *(uint2*)(orw + 2 * U + j0) = *(uint2*)t3;
            }
            signal_flag(fB + rb, t + 1);
            wait_ge(fB, NBLK_B, t + 1);      // all O rows ready
            // -------- P3: f = sigm(O@agg); state update; emit out --------
            {
                f32x4 p0 = {0.f, 0.f, 0.f, 0.f}, p1 = {0.f, 0.f, 0.f, 0.f};
                bf16x8 ob[4][8];
                LOADO(0, 0);
                LOADO(1, 1);
                LOADO(2, 2);
#pragma unroll
                for (int g = 0; g < 12; ++g) {
                    if (g < 9) LOADO(g + 3, (g + 3) & 3);
#pragma unroll
                    for (int j = 0; j < 8; ++j) {
                        const int ch = g * 8 + j;
                        const int kb = ch * 64 + q * 16;
                        const bf16x8 b = lds_rd(smem, ml, kb, RS_B);
                        if (j & 1) p1 = MFMA16(ob[g & 3][j], b, p1);
                        else       p0 = MFMA16(ob[g & 3][j], b, p0);
                    }
                }
                const f32x4 accv = p0 + p1;
                wait_ge(fA + 96, 64, t + 1);   // z3/z4 producers (cg 24..39)
                const int col = n0b + ml;
                const int r0 = w * 16 + q * 4;
#pragma unroll
                for (int r = 0; r < 4; ++r) {
                    const int row = r0 + r;
                    float z3 = bias[3 * U + col], z4 = bias[4 * U + col];
#pragma unroll
                    for (int kqi = 0; kqi < 4; ++kqi) {
                        const float* zr = zp + (size_t)kqi * 64 * N5 + row * N5;
                        z3 += zr[3 * U + col];
                        z4 += zr[4 * U + col];
                    }
                    const float f = sigm(accv[r]);
                    const float cold = c32[row * U + col];
                    const float cn = f * cold + (1.f - f) * tanhf(z4);
                    const float hn = z3 * tanhf(cn);
                    c32[row * U + col] = cn;
                    const bf16 chb = __float2bfloat16(cn);
                    const bf16 clb = __float2bfloat16(cn - __bfloat162float(chb));
                    const bf16 hhb = __float2bfloat16(hn);
                    const bf16 hlb = __float2bfloat16(hn - __bfloat162float(hhb));
                    abuf[0 * 65536 + row * U + col] = hhb;
                    abuf[1 * 65536 + row * U + col] = hlb;
                    abuf[2 * 65536 + row * U + col] = chb;
                    abuf[3 * 65536 + row * U + col] = clb;
                    out[(row * TSTEPS + t) * U + col] = hn;
                }
            }
            signal_flag(fC + rb, t + 1);
        }
#undef LOADO
    }
}

// ---------------------------------------------------------------------------
extern "C" void kernel_launch(void* const* d_in, const int* in_sizes, int n_in,
                              void* d_out, int out_size, void* d_ws, size_t ws_size,
                              hipStream_t stream) {
    (void)in_sizes; (void)n_in; (void)out_size; (void)ws_size;
    const float* x    = (const float*)d_in[0];
    const float* Wk   = (const float*)d_in[1];   // (256,5120)
    const float* Wr   = (const float*)d_in[2];   // (1024,5120)
    const float* Wc   = (const float*)d_in[3];   // (1024,5120)
    const float* bias = (const float*)d_in[4];   // (5120)
    const float* agg  = (const float*)d_in[5];   // (3072,1024)

    char* ws = (char*)d_ws;
    bf16*  wrct = (bf16*)(ws + OFF_WRC);
    bf16*  kt   = (bf16*)(ws + OFF_KT);
    bf16*  aggt = (bf16*)(ws + OFF_AGGT);
    bf16*  xbf  = (bf16*)(ws + OFF_XBF);
    float* zp   = (float*)(ws + OFF_ZP);
    bf16*  abuf = (bf16*)(ws + OFF_ABUF);
    float* c32  = (float*)(ws + OFF_C32);
    bf16*  obuf = (bf16*)(ws + OFF_OBUF);
    float* scal = (float*)(ws + OFF_SCAL);
    int*   ctr  = (int*)(ws + OFF_CTR);
    float* out  = (float*)d_out;

    hipMemsetAsync(abuf, 0, 4 * 65536 * sizeof(bf16), stream);
    hipMemsetAsync(c32, 0, BATCH * U * sizeof(float), stream);
    hipMemsetAsync(ctr, 0, 4096, stream);   // flags reset each launch

    // one-time conversions / transposes
    k_xconv<<<(BATCH * TSTEPS * DIM / 4 + 255) / 256, 256, 0, stream>>>(x, xbf, BATCH * TSTEPS * DIM / 4);
    k_transpose<<<dim3(5120 / 64, 1024 / 64), 256, 0, stream>>>(Wr, wrct, 5120, 2048, 0);
    k_transpose<<<dim3(5120 / 64, 1024 / 64), 256, 0, stream>>>(Wc, wrct, 5120, 2048, 1024);
    k_transpose<<<dim3(5120 / 64, 256 / 64),  256, 0, stream>>>(Wk, kt,   5120, 256, 0);
    k_transpose<<<dim3(1024 / 64, 3072 / 64), 256, 0, stream>>>(agg, aggt, 1024, 3072, 0);

    AttPtrs ap;
    for (int i = 0; i < 12; ++i) ap.p[i] = (const float*)d_in[6 + i];
    k_scal<<<1, 256, 0, stream>>>(ap, scal);

    // the whole recurrence: one persistent launch
    k_persist<<<NBLK, 256, 0, stream>>>(xbf, kt, wrct, aggt, zp, abuf, c32,
                                        obuf, scal, bias, out, ctr);
}